// Round 1
// baseline (1085.408 us; speedup 1.0000x reference)
//
#include <hip/hip_runtime.h>

#define SS 2048

typedef __attribute__((ext_vector_type(4))) float floatx4;
typedef __attribute__((ext_vector_type(8))) __bf16 bf16x8;

__device__ inline unsigned short f2bf(float f) {
  union { float f; unsigned u; } x; x.f = f;
  unsigned r = x.u + 0x7fffu + ((x.u >> 16) & 1u);
  return (unsigned short)(r >> 16);
}

// ---------------------------------------------------------------------------
// GEMM: out[m][n] = X[m][:] . W[n][:] + bias[n]   (X: [4096][1024] fp32,
// W: [1024][1024] fp32 row-major over n). mode 0: bf16 [b,h,s,dh];
// mode 1: bf16 [b,h,dh,s] (transposed for V); mode 2: fp32 [m][n].
// Tile 128x128, 4 waves (2x2), each wave 64x64 via 16 mfma_f32_16x16x32_bf16.
// ---------------------------------------------------------------------------
__global__ __launch_bounds__(256) void gemm_proj(
    const float* __restrict__ X, const float* __restrict__ W,
    const float* __restrict__ bias, void* __restrict__ outp, int mode)
{
  __shared__ unsigned short lA[128][40];  // pad 32->40: 2-way bank alias (free)
  __shared__ unsigned short lB[128][40];
  const int t = threadIdx.x;
  const int nb = blockIdx.x, mb = blockIdx.y;
  const int lane = t & 63, w = t >> 6;
  const int lr = lane & 15, lq = lane >> 4;
  const int wm = w >> 1, wn = w & 1;

  floatx4 acc[4][4];
  for (int j = 0; j < 4; ++j) {
    float bj = bias[nb * 128 + wn * 64 + j * 16 + lr];
    floatx4 bj4 = {bj, bj, bj, bj};
    for (int i = 0; i < 4; ++i) acc[i][j] = bj4;
  }

  for (int kc = 0; kc < 32; ++kc) {
    for (int i = 0; i < 4; ++i) {
      int idx = t + i * 256;          // 0..1023
      int row = idx >> 3, c4 = idx & 7;
      const float4 va = *(const float4*)&X[(size_t)(mb * 128 + row) * 1024 + kc * 32 + c4 * 4];
      *(ushort4*)&lA[row][c4 * 4] =
          make_ushort4(f2bf(va.x), f2bf(va.y), f2bf(va.z), f2bf(va.w));
      const float4 vb = *(const float4*)&W[(size_t)(nb * 128 + row) * 1024 + kc * 32 + c4 * 4];
      *(ushort4*)&lB[row][c4 * 4] =
          make_ushort4(f2bf(vb.x), f2bf(vb.y), f2bf(vb.z), f2bf(vb.w));
    }
    __syncthreads();
    bf16x8 aF[4], bF[4];
    for (int i = 0; i < 4; ++i)
      aF[i] = *(const bf16x8*)&lA[wm * 64 + i * 16 + lr][lq * 8];
    for (int j = 0; j < 4; ++j)
      bF[j] = *(const bf16x8*)&lB[wn * 64 + j * 16 + lr][lq * 8];
    for (int i = 0; i < 4; ++i)
      for (int j = 0; j < 4; ++j)
        acc[i][j] = __builtin_amdgcn_mfma_f32_16x16x32_bf16(aF[i], bF[j], acc[i][j], 0, 0, 0);
    __syncthreads();
  }

  if (mode == 2) {
    float* O = (float*)outp;
    for (int i = 0; i < 4; ++i) {
      int m0 = mb * 128 + wm * 64 + i * 16 + lq * 4;
      for (int j = 0; j < 4; ++j) {
        int n = nb * 128 + wn * 64 + j * 16 + lr;
        for (int r = 0; r < 4; ++r)
          O[(size_t)(m0 + r) * 1024 + n] = acc[i][j][r];
      }
    }
  } else if (mode == 0) {
    unsigned short* O = (unsigned short*)outp;
    for (int i = 0; i < 4; ++i) {
      int m0 = mb * 128 + wm * 64 + i * 16 + lq * 4;
      for (int j = 0; j < 4; ++j) {
        int n = nb * 128 + wn * 64 + j * 16 + lr;
        int h = n >> 6, dh = n & 63;
        for (int r = 0; r < 4; ++r) {
          int m = m0 + r;
          int b = m >> 11, s = m & 2047;
          O[((size_t)(b * 16 + h) * 2048 + s) * 64 + dh] = f2bf(acc[i][j][r]);
        }
      }
    }
  } else {  // mode 1: transposed [b][h][dh][s], 4 consecutive s -> 8B store
    unsigned short* O = (unsigned short*)outp;
    for (int i = 0; i < 4; ++i) {
      int m0 = mb * 128 + wm * 64 + i * 16 + lq * 4;
      int b = m0 >> 11, s0 = m0 & 2047;
      for (int j = 0; j < 4; ++j) {
        int n = nb * 128 + wn * 64 + j * 16 + lr;
        int h = n >> 6, dh = n & 63;
        *(ushort4*)&O[((size_t)(b * 16 + h) * 64 + dh) * 2048 + s0] =
            make_ushort4(f2bf(acc[i][j][0]), f2bf(acc[i][j][1]),
                         f2bf(acc[i][j][2]), f2bf(acc[i][j][3]));
      }
    }
  }
}

// ---------------------------------------------------------------------------
// Attention: per wave: one (b,h) and 32 query rows. Two passes over 64-key
// chunks: pass A row-sums exp(s/8); pass B recomputes scores, writes fp32
// probs to attn, stages bf16 p in LDS (A-layout) and accumulates ctx via MFMA.
// Barrier-free (per-wave LDS region); K/V read direct from global (L1/L2 hot).
// ---------------------------------------------------------------------------
__global__ __launch_bounds__(256) void attn_kernel(
    const unsigned short* __restrict__ Q, const unsigned short* __restrict__ K,
    const unsigned short* __restrict__ Vt, float* __restrict__ attn,
    float* __restrict__ ctx)
{
  __shared__ unsigned short pt[4][32][72];  // per-wave p tile, stride 72 (pad)
  const int t = threadIdx.x;
  const int w = t >> 6, lane = t & 63;
  const int lr = lane & 15, lq = lane >> 4;
  const int gw = blockIdx.x * 4 + w;   // 0..2047
  const int bh = gw >> 6;              // 0..31
  const int q0 = (gw & 63) * 32;       // query row base within S
  const int b = bh >> 4, h = bh & 15;

  const unsigned short* qp = Q + (size_t)bh * SS * 64;
  const unsigned short* kp = K + (size_t)bh * SS * 64;
  const unsigned short* vp = Vt + (size_t)bh * 64 * SS;
  float* aout = attn + (size_t)bh * SS * SS;

  bf16x8 qF[2][2];
  for (int mt = 0; mt < 2; ++mt)
    for (int kk = 0; kk < 2; ++kk)
      qF[mt][kk] = *(const bf16x8*)&qp[(size_t)(q0 + mt * 16 + lr) * 64 + kk * 32 + lq * 8];

  const floatx4 zf = {0.f, 0.f, 0.f, 0.f};
  float lsum[2][4] = {{0.f, 0.f, 0.f, 0.f}, {0.f, 0.f, 0.f, 0.f}};

  // ---- pass A: row sums of exp(s * 0.125) ----
  for (int kc = 0; kc < 32; ++kc) {
    for (int nt = 0; nt < 4; ++nt) {
      const size_t kbase = (size_t)(kc * 64 + nt * 16 + lr) * 64 + lq * 8;
      bf16x8 kF0 = *(const bf16x8*)&kp[kbase];
      bf16x8 kF1 = *(const bf16x8*)&kp[kbase + 32];
      for (int mt = 0; mt < 2; ++mt) {
        floatx4 s = __builtin_amdgcn_mfma_f32_16x16x32_bf16(qF[mt][0], kF0, zf, 0, 0, 0);
        s = __builtin_amdgcn_mfma_f32_16x16x32_bf16(qF[mt][1], kF1, s, 0, 0, 0);
        for (int r = 0; r < 4; ++r)
          lsum[mt][r] += __expf(s[r] * 0.125f);
      }
    }
  }
  float rl[2][4];
  for (int mt = 0; mt < 2; ++mt)
    for (int r = 0; r < 4; ++r) {
      float v = lsum[mt][r];
      v += __shfl_xor(v, 1);
      v += __shfl_xor(v, 2);
      v += __shfl_xor(v, 4);
      v += __shfl_xor(v, 8);
      rl[mt][r] = 1.0f / v;
    }

  floatx4 oF[2][4];
  for (int mt = 0; mt < 2; ++mt)
    for (int nt = 0; nt < 4; ++nt) oF[mt][nt] = zf;

  // ---- pass B: recompute, write probs, accumulate ctx ----
  for (int kc = 0; kc < 32; ++kc) {
    for (int nt = 0; nt < 4; ++nt) {
      const size_t kbase = (size_t)(kc * 64 + nt * 16 + lr) * 64 + lq * 8;
      bf16x8 kF0 = *(const bf16x8*)&kp[kbase];
      bf16x8 kF1 = *(const bf16x8*)&kp[kbase + 32];
      for (int mt = 0; mt < 2; ++mt) {
        floatx4 s = __builtin_amdgcn_mfma_f32_16x16x32_bf16(qF[mt][0], kF0, zf, 0, 0, 0);
        s = __builtin_amdgcn_mfma_f32_16x16x32_bf16(qF[mt][1], kF1, s, 0, 0, 0);
        for (int r = 0; r < 4; ++r) {
          float p = __expf(s[r] * 0.125f) * rl[mt][r];
          int row = mt * 16 + lq * 4 + r;
          aout[(size_t)(q0 + row) * 2048 + kc * 64 + nt * 16 + lr] = p;
          pt[w][row][nt * 16 + lr] = f2bf(p);
        }
      }
    }
    for (int kk = 0; kk < 2; ++kk) {
      bf16x8 aP[2];
      for (int mt = 0; mt < 2; ++mt)
        aP[mt] = *(const bf16x8*)&pt[w][mt * 16 + lr][kk * 32 + lq * 8];
      for (int nt = 0; nt < 4; ++nt) {
        bf16x8 vF = *(const bf16x8*)&vp[(size_t)(nt * 16 + lr) * 2048 + kc * 64 + kk * 32 + lq * 8];
        for (int mt = 0; mt < 2; ++mt)
          oF[mt][nt] = __builtin_amdgcn_mfma_f32_16x16x32_bf16(aP[mt], vF, oF[mt][nt], 0, 0, 0);
      }
    }
  }

  // ctx[b*2048+row][h*64+dh] fp32
  for (int mt = 0; mt < 2; ++mt)
    for (int nt = 0; nt < 4; ++nt)
      for (int r = 0; r < 4; ++r) {
        int row = q0 + mt * 16 + lq * 4 + r;
        int col = h * 64 + nt * 16 + lr;
        ctx[(size_t)(b * 2048 + row) * 1024 + col] = oF[mt][nt][r];
      }
}

extern "C" void kernel_launch(void* const* d_in, const int* in_sizes, int n_in,
                              void* d_out, int out_size, void* d_ws, size_t ws_size,
                              hipStream_t stream) {
  (void)in_sizes; (void)n_in; (void)out_size; (void)ws_size;
  const float* query = (const float*)d_in[0];
  const float* key   = (const float*)d_in[1];
  const float* value = (const float*)d_in[2];
  const float* Wq = (const float*)d_in[3];
  const float* bq = (const float*)d_in[4];
  const float* Wk = (const float*)d_in[5];
  const float* bk = (const float*)d_in[6];
  const float* Wv = (const float*)d_in[7];
  const float* bv = (const float*)d_in[8];
  const float* Wo = (const float*)d_in[9];
  const float* bo = (const float*)d_in[10];
  float* outF = (float*)d_out;

  // workspace: q_s, k_s (bf16 [b,h,s,dh]); v_t (bf16 [b,h,dh,s]); ctx fp32
  unsigned short* q_s = (unsigned short*)d_ws;
  unsigned short* k_s = q_s + 4194304;
  unsigned short* v_t = k_s + 4194304;
  float* ctx = (float*)(v_t + 4194304);

  dim3 gg(8, 32), bb(256);
  gemm_proj<<<gg, bb, 0, stream>>>(query, Wq, bq, (void*)q_s, 0);
  gemm_proj<<<gg, bb, 0, stream>>>(key,   Wk, bk, (void*)k_s, 0);
  gemm_proj<<<gg, bb, 0, stream>>>(value, Wv, bv, (void*)v_t, 1);
  attn_kernel<<<dim3(512), bb, 0, stream>>>(q_s, k_s, v_t, outF + 4194304, ctx);
  gemm_proj<<<gg, bb, 0, stream>>>(ctx, Wo, bo, (void*)outF, 2);
}